// Round 19
// baseline (54.433 us; speedup 1.0000x reference)
//
#include <hip/hip_runtime.h>

typedef __attribute__((ext_vector_type(8))) short bf16x8;
typedef __attribute__((ext_vector_type(4))) float f32x4;

constexpr int TN = 8192;   // tokens
constexpr int DN = 4096;   // model dim
constexpr int EN = 64;     // experts

constexpr int NS     = DN / 32;     // 128 K32 slots total
constexpr int KSPLIT = 8;           // k-eighth per block
constexpr int SLOTS  = NS / KSPLIT; // 16 K32 slots per block (512 k)
constexpr int RB     = 256;         // rows per block (8 waves x 32)

__device__ __forceinline__ unsigned short f2bf(float f) {  // RNE f32->bf16
    unsigned u = __builtin_bit_cast(unsigned, f);
    u += 0x7FFFu + ((u >> 16) & 1u);
    return (unsigned short)(u >> 16);
}
__device__ __forceinline__ float bf2f(unsigned short h) {
    unsigned u = ((unsigned)h) << 16;
    return __builtin_bit_cast(float, u);
}

// Kernel 0: split wg into hi/lo bf16 planes in MFMA-fragment order WITH the
// phi k-permutation (slot j of lane-group g holds k = s*32 + (j<4 ? g*4+j
// : 16+g*4+(j-4))) so the GEMM's A loads are sector-contiguous (R17 win).
__global__ __launch_bounds__(256)
void wg_frag_kernel(const float* __restrict__ wg, unsigned short* __restrict__ BF) {
    const int gid = blockIdx.x * 256 + threadIdx.x;  // 65536 items
    const int l  = gid & 63;
    const int et = (gid >> 6) & 3;
    const int s  = (gid >> 8) & (NS - 1);
    const int p  = gid >> 15;
    const int e  = et * 16 + (l & 15);
    const int k  = s * 32 + (l >> 4) * 4;            // phi base

    const float* src = wg + (size_t)e * DN + k;
    float4 v0 = *reinterpret_cast<const float4*>(src);        // slots 0..3
    float4 v1 = *reinterpret_cast<const float4*>(src + 16);   // slots 4..7
    float f[8] = {v0.x, v0.y, v0.z, v0.w, v1.x, v1.y, v1.z, v1.w};
    unsigned short o[8];
#pragma unroll
    for (int j = 0; j < 8; ++j) {
        unsigned short h = f2bf(f[j]);
        o[j] = p ? f2bf(f[j] - bf2f(h)) : h;
    }
    unsigned short* dst = BF + (((size_t)p * NS + s) * 4 + et) * 512 + (size_t)l * 8;
    *reinterpret_cast<ushort4*>(dst)     = make_ushort4(o[0], o[1], o[2], o[3]);
    *reinterpret_cast<ushort4*>(dst + 4) = make_ushort4(o[4], o[5], o[6], o[7]);
}

// Kernel 1: B-in-LDS split-bf16 MFMA GEMM, K-eighth blocks.
// Grid = 32 row-tiles x 8 ksplits = 256 blocks (1/CU), 512 thr = 8 waves.
// Block owns 16 K32 slots; its B (hi+lo, 128KB) staged into LDS ONCE -- B
// leaves the TCP path (per-CU vector-memory bytes 1.5MB -> 0.64MB at the
// measured ~24 B/cyc/CU pace). Wave w owns 32 rows (2 halves, acc 32 VGPR)
// and iterates all 16 slots independently (no in-loop barriers). A
// gathered per-lane from x with the phi sector layout, hi/lo split
// in-register; A depth-3 (vmcnt FIFO, 3-phase slack), B depth-2 via
// conflict-free ds_read_b128 (next-slot issued before compute's wait).
// ks = bid&7 matches XCD round-robin -> one 256KB B-eighth per XCD L2.
__global__ __launch_bounds__(512, 1)
void gate_gemm_kernel(const float* __restrict__ x,
                      const unsigned short* __restrict__ BF,
                      float* __restrict__ part) {
    __shared__ uint4 LB[SLOTS * 2 * 256];  // 128 KB: [slot][plane][et*64+lane]

    const int tid  = threadIdx.x;
    const int lane = tid & 63;
    const int w    = tid >> 6;          // wave 0..7
    const int rt   = blockIdx.x >> 3;
    const int ks   = blockIdx.x & 7;
    const int r0   = rt * RB;

    const int fr = lane & 15;           // fragment row (A) / expert col (B)
    const int g  = lane >> 4;           // k-group

    // stage B-eighth: 8192 uint4 (128KB), 16 iters x 512 threads, coalesced
    {
        const uint4* gsrc = reinterpret_cast<const uint4*>(BF);
#pragma unroll
        for (int i = 0; i < SLOTS * 2 * 256 / 512; ++i) {   // 16 iters
            int e = tid + i * 512;
            int j = e & 255, p = (e >> 8) & 1, s = e >> 9;
            LB[e] = gsrc[((size_t)p * NS + ks * SLOTS + s) * 256 + j];
        }
    }
    __syncthreads();                    // only barrier; LDS read-only after

    // phi-permuted A base: row r0 + w*32 + fr, + g*4 floats per 32-float slot
    const float* xa = x + (size_t)(r0 + w * 32 + fr) * DN + g * 4;

    f32x4 acc[2][4] = {};               // [row-half][expert-tile] (32 VGPR)
    float4 XA[3][2][2];                 // depth-3 A fp32 [set][rh][sector]
    bf16x8 Bh[2][4], Bl[2][4];          // depth-2 B from LDS (64 VGPR)

    auto loadA = [&](int set, int t) {
        const float* p = xa + (size_t)(ks * SLOTS + t) * 32;
#pragma unroll
        for (int rh = 0; rh < 2; ++rh) {
            const float* pr = p + (size_t)rh * 16 * DN;
            XA[set][rh][0] = *reinterpret_cast<const float4*>(pr);        // sector 0
            XA[set][rh][1] = *reinterpret_cast<const float4*>(pr + 16);   // sector 1
        }
    };
    auto loadB = [&](int set, int t) {  // ds_read_b128 x8, conflict-free
#pragma unroll
        for (int et = 0; et < 4; ++et)
            Bh[set][et] = __builtin_bit_cast(bf16x8, LB[(t * 2 + 0) * 256 + et * 64 + lane]);
#pragma unroll
        for (int et = 0; et < 4; ++et)
            Bl[set][et] = __builtin_bit_cast(bf16x8, LB[(t * 2 + 1) * 256 + et * 64 + lane]);
    };
    auto compute = [&](int aset, int bset) {
        bf16x8 ah[2], al[2];
#pragma unroll
        for (int rh = 0; rh < 2; ++rh) {
            float f[8] = {XA[aset][rh][0].x, XA[aset][rh][0].y,
                          XA[aset][rh][0].z, XA[aset][rh][0].w,
                          XA[aset][rh][1].x, XA[aset][rh][1].y,
                          XA[aset][rh][1].z, XA[aset][rh][1].w};
#pragma unroll
            for (int j = 0; j < 8; ++j) {
                unsigned short hh = f2bf(f[j]);
                ah[rh][j] = (short)hh;
                al[rh][j] = (short)f2bf(f[j] - bf2f(hh));
            }
        }
#pragma unroll
        for (int et = 0; et < 4; ++et)
#pragma unroll
            for (int rh = 0; rh < 2; ++rh) {
                acc[rh][et] = __builtin_amdgcn_mfma_f32_16x16x32_bf16(ah[rh], Bh[bset][et], acc[rh][et], 0, 0, 0);
                acc[rh][et] = __builtin_amdgcn_mfma_f32_16x16x32_bf16(al[rh], Bh[bset][et], acc[rh][et], 0, 0, 0);
                acc[rh][et] = __builtin_amdgcn_mfma_f32_16x16x32_bf16(ah[rh], Bl[bset][et], acc[rh][et], 0, 0, 0);
                acc[rh][et] = __builtin_amdgcn_mfma_f32_16x16x32_bf16(al[rh], Bl[bset][et], acc[rh][et], 0, 0, 0);
            }
    };

    // prologue: A(0..2) in flight (vmcnt), B(0) from LDS (lgkm)
    loadA(0, 0);
    loadA(1, 1);
    loadA(2, 2);
    loadB(0, 0);
#pragma unroll
    for (int t = 0; t < SLOTS; ++t) {   // full unroll: set indices static
        if (t + 1 < SLOTS) loadB((t + 1) & 1, t + 1);  // younger lgkm: no drain
        compute(t % 3, t & 1);          // waits A(t) (vmcnt, 3-phase slack)
        if (t + 3 < SLOTS) loadA(t % 3, t + 3);
        asm volatile("" ::: "memory");  // pin per-phase issue order
    }

    // partial store straight from registers (each wave owns distinct rows).
    // C/D layout: col = lane&15, row = (lane>>4)*4 + reg  [m89]
    float* dst = part + ((size_t)ks * TN + r0 + w * 32) * EN;
#pragma unroll
    for (int rh = 0; rh < 2; ++rh)
#pragma unroll
        for (int et = 0; et < 4; ++et)
#pragma unroll
            for (int r = 0; r < 4; ++r)
                dst[(size_t)(rh * 16 + g * 4 + r) * EN + et * 16 + fr] = acc[rh][et][r];
}

// Kernel 2: sum 8 partials, top-1 softmax per row.
// out[0..TN) = argmax index (as float), out[TN..2TN) = max gate = 1/sumexp.
__global__ __launch_bounds__(256)
void top1_softmax_kernel(const float* __restrict__ part, float* __restrict__ out) {
    const int row = blockIdx.x * blockDim.x + threadIdx.x;
    if (row >= TN) return;

    float v[EN];
#pragma unroll
    for (int i = 0; i < EN / 4; ++i) {
        float4 s = *reinterpret_cast<const float4*>(&part[(size_t)row * EN + i * 4]);
#pragma unroll
        for (int h = 1; h < KSPLIT; ++h) {
            float4 t = *reinterpret_cast<const float4*>(
                &part[((size_t)h * TN + row) * EN + i * 4]);
            s.x += t.x; s.y += t.y; s.z += t.z; s.w += t.w;
        }
        v[i * 4 + 0] = s.x; v[i * 4 + 1] = s.y;
        v[i * 4 + 2] = s.z; v[i * 4 + 3] = s.w;
    }

    float m = v[0];
    int idx = 0;
#pragma unroll
    for (int e = 1; e < EN; ++e)
        if (v[e] > m) { m = v[e]; idx = e; }  // strict >: first occurrence = jnp.argmax
    float s = 0.0f;
#pragma unroll
    for (int e = 0; e < EN; ++e) s += __expf(v[e] - m);

    out[row]      = (float)idx;
    out[TN + row] = 1.0f / s;
}

extern "C" void kernel_launch(void* const* d_in, const int* in_sizes, int n_in,
                              void* d_out, int out_size, void* d_ws, size_t ws_size,
                              hipStream_t stream) {
    const float* x  = (const float*)d_in[0];
    const float* wg = (const float*)d_in[1];
    float* out = (float*)d_out;

    constexpr size_t BF_BYTES = (size_t)2 * NS * 4 * 512 * 2;  // 1 MB
    unsigned short* BF = (unsigned short*)d_ws;
    float* part = (float*)((char*)d_ws + BF_BYTES);            // 16 MB partials

    wg_frag_kernel<<<dim3(256), dim3(256), 0, stream>>>(wg, BF);
    gate_gemm_kernel<<<dim3((TN / RB) * KSPLIT), dim3(512), 0, stream>>>(x, BF, part);
    top1_softmax_kernel<<<dim3(TN / 256), dim3(256), 0, stream>>>(part, out);
}

// Round 20
// 37.522 us; speedup vs baseline: 1.4507x; 1.4507x over previous
//
#include <hip/hip_runtime.h>

typedef __attribute__((ext_vector_type(8))) short bf16x8;
typedef __attribute__((ext_vector_type(4))) float f32x4;

constexpr int TN = 8192;   // tokens
constexpr int DN = 4096;   // model dim
constexpr int EN = 64;     // experts

constexpr int BM = 32;         // rows per block
constexpr int NS = DN / 32;    // 128 MFMA K32 slots
constexpr int NT = 16;         // slots per wave (128 / 8 waves)

__device__ __forceinline__ unsigned short f2bf(float f) {  // RNE f32->bf16
    unsigned u = __builtin_bit_cast(unsigned, f);
    u += 0x7FFFu + ((u >> 16) & 1u);
    return (unsigned short)(u >> 16);
}
__device__ __forceinline__ float bf2f(unsigned short h) {
    unsigned u = ((unsigned)h) << 16;
    return __builtin_bit_cast(float, u);
}

// Kernel 0: split wg into hi/lo bf16 planes in MFMA-fragment order WITH the
// phi k-permutation: fragment slot j of lane-group g holds physical k =
// s*32 + (j<4 ? g*4+j : 16+g*4+(j-4)). Same phi is used by the GEMM's A
// loads (dot product invariant when both operands share the permutation),
// making every A global-load instruction cover ONE 64B sector per row.
__global__ __launch_bounds__(256)
void wg_frag_kernel(const float* __restrict__ wg, unsigned short* __restrict__ BF) {
    const int gid = blockIdx.x * 256 + threadIdx.x;  // 65536 items
    const int l  = gid & 63;
    const int et = (gid >> 6) & 3;
    const int s  = (gid >> 8) & (NS - 1);
    const int p  = gid >> 15;
    const int e  = et * 16 + (l & 15);
    const int k  = s * 32 + (l >> 4) * 4;            // phi base

    const float* src = wg + (size_t)e * DN + k;
    float4 v0 = *reinterpret_cast<const float4*>(src);        // slots 0..3
    float4 v1 = *reinterpret_cast<const float4*>(src + 16);   // slots 4..7
    float f[8] = {v0.x, v0.y, v0.z, v0.w, v1.x, v1.y, v1.z, v1.w};
    unsigned short o[8];
#pragma unroll
    for (int j = 0; j < 8; ++j) {
        unsigned short h = f2bf(f[j]);
        o[j] = p ? f2bf(f[j] - bf2f(h)) : h;
    }
    unsigned short* dst = BF + (((size_t)p * NS + s) * 4 + et) * 512 + (size_t)l * 8;
    *reinterpret_cast<ushort4*>(dst)     = make_ushort4(o[0], o[1], o[2], o[3]);
    *reinterpret_cast<ushort4*>(dst + 4) = make_ushort4(o[4], o[5], o[6], o[7]);
}

// Kernel 1: barrier-free direct-gather split-bf16 MFMA GEMM + fused top-1.
// Grid = 256 blocks (1/CU), 512 threads = 8 INDEPENDENT waves (no in-loop
// __syncthreads). Wave w = (kq=w&3, kh=w>>2) owns K32 slots kh*64+t*4+kq,
// and computes both 16-row halves. A-fragments gathered per-lane from x
// using the phi k-permutation: lane (fr,g) instr0 reads row-bytes
// [s*128 + g*16 .. +16) (4 lane-groups = one 64B sector), instr1 the
// second sector -- 16 sector-touches/instr, the dense minimum (was 32).
// hi/lo split in-register; A depth-3 / B depth-2 ping-pong, full unroll.
__global__ __launch_bounds__(512, 2)
void gate_fused_kernel(const float* __restrict__ x,
                       const unsigned short* __restrict__ BF,
                       float* __restrict__ out) {
    __shared__ float L[8][BM][68];      // 69632 B; per-wave partial logits

    const int tid  = threadIdx.x;
    const int lane = tid & 63;
    const int w    = tid >> 6;          // wave 0..7
    const int kq   = w & 3;
    const int kh   = w >> 2;
    const int r0   = blockIdx.x * BM;

    const int fr = lane & 15;           // fragment row (A) / expert col (B)
    const int g  = lane >> 4;           // k-group

    // phi-permuted A base: row r0+fr, + g*4 floats within each 32-float slot
    const float* xa = x + (size_t)(r0 + fr) * DN + g * 4;

    f32x4 acc[2][4] = {};               // [row-half][expert-tile]

    float4 XA[3][2][2];                 // depth-3 A fp32 ([set][rh][2x float4])
    bf16x8 Bq[2][8];                    // depth-2 B ([set][et]=hi, [set][4+et]=lo)

    auto loadA = [&](int set, int t) {
        const int s = kh * 64 + t * 4 + kq;
        const float* p = xa + (size_t)s * 32;
#pragma unroll
        for (int rh = 0; rh < 2; ++rh) {
            const float* pr = p + (size_t)rh * 16 * DN;
            XA[set][rh][0] = *reinterpret_cast<const float4*>(pr);       // sector 0
            XA[set][rh][1] = *reinterpret_cast<const float4*>(pr + 16);  // sector 1
        }
    };
    auto loadB = [&](int set, int t) {
        const int s = kh * 64 + t * 4 + kq;
        const unsigned short* bp = BF + (size_t)s * 2048 + (size_t)lane * 8;
#pragma unroll
        for (int et = 0; et < 4; ++et)
            Bq[set][et] = *reinterpret_cast<const bf16x8*>(bp + et * 512);
#pragma unroll
        for (int et = 0; et < 4; ++et)
            Bq[set][4 + et] = *reinterpret_cast<const bf16x8*>(bp + (size_t)NS * 2048 + et * 512);
    };
    auto compute = [&](int aset, int bset) {
        bf16x8 ah[2], al[2];
#pragma unroll
        for (int rh = 0; rh < 2; ++rh) {
            float f[8] = {XA[aset][rh][0].x, XA[aset][rh][0].y,
                          XA[aset][rh][0].z, XA[aset][rh][0].w,
                          XA[aset][rh][1].x, XA[aset][rh][1].y,
                          XA[aset][rh][1].z, XA[aset][rh][1].w};
#pragma unroll
            for (int j = 0; j < 8; ++j) {
                unsigned short hh = f2bf(f[j]);
                ah[rh][j] = (short)hh;
                al[rh][j] = (short)f2bf(f[j] - bf2f(hh));
            }
        }
#pragma unroll
        for (int et = 0; et < 4; ++et)
#pragma unroll
            for (int rh = 0; rh < 2; ++rh) {
                acc[rh][et] = __builtin_amdgcn_mfma_f32_16x16x32_bf16(ah[rh], Bq[bset][et],     acc[rh][et], 0, 0, 0);
                acc[rh][et] = __builtin_amdgcn_mfma_f32_16x16x32_bf16(al[rh], Bq[bset][et],     acc[rh][et], 0, 0, 0);
                acc[rh][et] = __builtin_amdgcn_mfma_f32_16x16x32_bf16(ah[rh], Bq[bset][4 + et], acc[rh][et], 0, 0, 0);
                acc[rh][et] = __builtin_amdgcn_mfma_f32_16x16x32_bf16(al[rh], Bq[bset][4 + et], acc[rh][et], 0, 0, 0);
            }
    };

    // prologue FIFO: B(0), A(0), B(1), A(1), A(2)
    loadB(0, 0);
    loadA(0, 0);
    loadB(1, 1);
    loadA(1, 1);
    loadA(2, 2);
#pragma unroll
    for (int t = 0; t < NT; ++t) {      // full unroll: set indices static
        compute(t % 3, t & 1);
        if (t + 2 < NT) loadB(t & 1, t + 2);   // B BEFORE A (FIFO order)
        if (t + 3 < NT) loadA(t % 3, t + 3);
        asm volatile("" ::: "memory");  // pin per-phase issue order
    }

    // epilogue: per-wave partial logits to LDS, then fused top-1 softmax
#pragma unroll
    for (int rh = 0; rh < 2; ++rh)
#pragma unroll
        for (int et = 0; et < 4; ++et)
#pragma unroll
            for (int r = 0; r < 4; ++r)
                // C/D layout: col = lane&15, row = (lane>>4)*4 + reg  [m89]
                L[w][rh * 16 + g * 4 + r][et * 16 + fr] = acc[rh][et][r];
    __syncthreads();

    {
        const int row = tid >> 4;       // 0..31
        const int eg  = tid & 15;       // 4 experts each
        float v[4];
#pragma unroll
        for (int j = 0; j < 4; ++j) {
            float s = L[0][row][eg * 4 + j];
#pragma unroll
            for (int q = 1; q < 8; ++q) s += L[q][row][eg * 4 + j];
            v[j] = s;
        }
        float m = v[0];
        int idx = eg * 4;
#pragma unroll
        for (int j = 1; j < 4; ++j)
            if (v[j] > m) { m = v[j]; idx = eg * 4 + j; }  // strict >: first occurrence
#pragma unroll
        for (int d = 1; d < 16; d <<= 1) {
            float om = __shfl_xor(m, d);
            int   oi = __shfl_xor(idx, d);
            if (om > m || (om == m && oi < idx)) { m = om; idx = oi; }
        }
        float s = 0.0f;
#pragma unroll
        for (int j = 0; j < 4; ++j) s += __expf(v[j] - m);
#pragma unroll
        for (int d = 1; d < 16; d <<= 1) s += __shfl_xor(s, d);
        if (eg == 0) {
            out[r0 + row]      = (float)idx;     // argmax index
            out[TN + r0 + row] = 1.0f / s;       // max gate = 1/sum(exp(l-lmax))
        }
    }
}

extern "C" void kernel_launch(void* const* d_in, const int* in_sizes, int n_in,
                              void* d_out, int out_size, void* d_ws, size_t ws_size,
                              hipStream_t stream) {
    const float* x  = (const float*)d_in[0];
    const float* wg = (const float*)d_in[1];
    float* out = (float*)d_out;

    unsigned short* BF = (unsigned short*)d_ws;  // 1 MB fragment-ordered hi/lo

    wg_frag_kernel<<<dim3(256), dim3(256), 0, stream>>>(wg, BF);
    gate_fused_kernel<<<dim3(TN / BM), dim3(512), 0, stream>>>(x, BF, out);
}